// Round 4
// baseline (377.266 us; speedup 1.0000x reference)
//
#include <hip/hip_runtime.h>
#include <hip/hip_bf16.h>

typedef short bf16x8 __attribute__((ext_vector_type(8)));
typedef float f32x4 __attribute__((ext_vector_type(4)));
typedef unsigned short ushort_t;

#define NH 16
#define HD 128
#define SEQ 2048
#define HID 2048
#define NQKV 6144
#define BATCH 2

__device__ __forceinline__ ushort_t f2bf(float x) {
    unsigned u = __builtin_bit_cast(unsigned, x);
    u = (u + 0x7fffu + ((u >> 16) & 1u)) >> 16;
    return (ushort_t)u;
}

// async global->LDS, 16B per lane. LDS dest = wave-uniform base + lane*16.
__device__ __forceinline__ void gl2lds16(const ushort_t* g, ushort_t* l) {
    __builtin_amdgcn_global_load_lds(
        (__attribute__((address_space(1))) void*)(g),
        (__attribute__((address_space(3))) void*)(l), 16, 0, 0);
}

// ---------------------------------------------------------------------------
// fp32 -> bf16 elementwise (hidden states), 8 elems/thread
// ---------------------------------------------------------------------------
__global__ __launch_bounds__(256) void to_bf16(
    const float* __restrict__ x, ushort_t* __restrict__ y, int n8) {
    int i = blockIdx.x * 256 + threadIdx.x;
    if (i >= n8) return;
    float4 a0 = *(const float4*)(x + (size_t)i * 8);
    float4 a1 = *(const float4*)(x + (size_t)i * 8 + 4);
    union { ushort_t u[8]; uint4 v; } p;
    p.u[0]=f2bf(a0.x); p.u[1]=f2bf(a0.y); p.u[2]=f2bf(a0.z); p.u[3]=f2bf(a0.w);
    p.u[4]=f2bf(a1.x); p.u[5]=f2bf(a1.y); p.u[6]=f2bf(a1.z); p.u[7]=f2bf(a1.w);
    *(uint4*)(y + (size_t)i * 8) = p.v;
}

// ---------------------------------------------------------------------------
// Transpose + fp32->bf16: w [K][N] -> wT [N][K] bf16
// ---------------------------------------------------------------------------
__global__ __launch_bounds__(256) void transpose_to_bf16(
    const float* __restrict__ w, ushort_t* __restrict__ wT, int K, int N) {
    __shared__ float tile[32][33];
    int nb = blockIdx.x * 32, kb = blockIdx.y * 32;
    int tx = threadIdx.x, ty = threadIdx.y;  // 32 x 8
#pragma unroll
    for (int i = 0; i < 4; ++i) {
        int k = kb + ty + i * 8;
        tile[ty + i * 8][tx] = w[(size_t)k * N + nb + tx];
    }
    __syncthreads();
#pragma unroll
    for (int i = 0; i < 4; ++i) {
        int n = nb + ty + i * 8;
        wT[(size_t)n * K + kb + tx] = f2bf(tile[tx][ty + i * 8]);
    }
}

// ---------------------------------------------------------------------------
// m97-style GEMM core (kept for gemm_proj): 128x128 tile, BK=64.
// ---------------------------------------------------------------------------
#define GEMM_KLOOP(A_, BT_)                                                     \
    const int t = threadIdx.x;                                                  \
    const int w = t >> 6, lane = t & 63, lm = lane & 15, lq = lane >> 4;        \
    const int wm = (w >> 1) * 64, wn = (w & 1) * 64;                            \
    const int lrow = lane >> 3, lsw = (lane & 7) ^ lrow;                        \
    f32x4 acc[4][4] = {};                                                       \
    const ushort_t* gA = A_ + (size_t)(mb + w * 32 + lrow) * HID + lsw * 8;     \
    const ushort_t* gB = BT_ + (size_t)(nb + w * 32 + lrow) * HID + lsw * 8;    \
    for (int kb = 0; kb < HID; kb += 64) {                                      \
        __syncthreads();                                                        \
        _Pragma("unroll")                                                       \
        for (int c = 0; c < 4; ++c) {                                           \
            gl2lds16(gA + (size_t)c * 8 * HID + kb, At + (w * 256 + c * 64) * 8); \
            gl2lds16(gB + (size_t)c * 8 * HID + kb, Bt + (w * 256 + c * 64) * 8); \
        }                                                                       \
        __syncthreads();                                                        \
        _Pragma("unroll")                                                       \
        for (int kc = 0; kc < 2; ++kc) {                                        \
            const int slot = (kc * 4 + lq) ^ (lm & 7);                          \
            bf16x8 af[4], bfr[4];                                               \
            _Pragma("unroll")                                                   \
            for (int mt = 0; mt < 4; ++mt)                                      \
                af[mt] = ((const bf16x8*)At)[(wm + mt * 16 + lm) * 8 + slot];   \
            _Pragma("unroll")                                                   \
            for (int nt = 0; nt < 4; ++nt)                                      \
                bfr[nt] = ((const bf16x8*)Bt)[(wn + nt * 16 + lm) * 8 + slot];  \
            _Pragma("unroll")                                                   \
            for (int mt = 0; mt < 4; ++mt)                                      \
                _Pragma("unroll")                                               \
                for (int nt = 0; nt < 4; ++nt)                                  \
                    acc[mt][nt] = __builtin_amdgcn_mfma_f32_16x16x32_bf16(      \
                        af[mt], bfr[nt], acc[mt][nt], 0, 0, 0);                 \
        }                                                                       \
    }

// ---------------------------------------------------------------------------
// GEMM 1 (8-phase 256x256 template, T2+T3+T4+T5):
// qkv = hidden(bf16) @ w_qkv + b_qkv.
// 512 thr = 8 waves (2M x 4N); per-wave C = 128x64 (8x4 16x16 frags).
// LDS 128KB = [A|B][buf0|buf1][kh0|kh1], unit = 16KB (256 rows x 32 k).
// Unit layout: slot = r*4 + (c ^ ((r>>1)&3)), 16B chunks (bank-conflict-free
// ds_read_b128; inverse swizzle applied on the global source of gl2lds).
// Per iteration: consume tiles Ta=2i (buf0, ph1-4) and Tb=2i+1 (buf1, ph5-8);
// each phase = {stage 1 half (2 gl2lds), ds_read frags, barrier, 16 MFMA
// (setprio), [vmcnt(8) on even phases], barrier}. Staging order per iter:
// ph1:A[b1][kh1]<-Tb ph2:B[b1][kh1]<-Tb ph3:A[b0][kh0]<-Ta+2 ph4:B[b0][kh0]
// ph5:A[b0][kh1]<-Ta+2 ph6:B[b0][kh1] ph7:A[b1][kh0]<-Tb+2 ph8:B[b1][kh0].
// Every region is overwritten >=1 closing-barrier after its last ds_read;
// vmcnt(8) = (12 max outstanding) - (oldest 4 needed) at each even phase.
// Tail iterations stage wrapped tiles (&31) so vmcnt counts stay uniform.
// ---------------------------------------------------------------------------
#define QSTAGE(GOP, OPIDX, SBUF, SKH, STILE)                                  \
    _Pragma("unroll")                                                         \
    for (int j = 0; j < 2; ++j)                                               \
        gl2lds16(GOP + soff[j] + (STILE) * 64 + (SKH) * 32,                   \
                 lds + (OPIDX) * 32768 + ((SBUF) * 2 + (SKH)) * 8192 +        \
                     (j * 512 + w * 64) * 8);

#define QLDA(BUF, KH)                                                         \
    _Pragma("unroll")                                                         \
    for (int mf = 0; mf < 8; ++mf) {                                          \
        int rr = wm + mf * 16 + lm;                                           \
        int slot = rr * 4 + (lq ^ ((rr >> 1) & 3));                           \
        af[mf] = *(const bf16x8*)&lds[((BUF) * 2 + (KH)) * 8192 + slot * 8];  \
    }

#define QLDB(BUF, KH, NHALF)                                                  \
    _Pragma("unroll")                                                         \
    for (int nj = 0; nj < 2; ++nj) {                                          \
        int rr = wn + ((NHALF) * 2 + nj) * 16 + lm;                           \
        int slot = rr * 4 + (lq ^ ((rr >> 1) & 3));                           \
        bfr[nj] = *(const bf16x8*)&lds[32768 + ((BUF) * 2 + (KH)) * 8192 + slot * 8]; \
    }

#define QPHASE(BUF, KH, NHALF, READA, GOP, OPIDX, SBUF, SKH, STILE, DRAIN)    \
    QSTAGE(GOP, OPIDX, SBUF, SKH, STILE)                                      \
    if (READA) { QLDA(BUF, KH) }                                              \
    QLDB(BUF, KH, NHALF)                                                      \
    asm volatile("" ::: "memory");                                            \
    __builtin_amdgcn_s_barrier();                                             \
    __builtin_amdgcn_sched_barrier(0);                                        \
    __builtin_amdgcn_s_setprio(1);                                            \
    _Pragma("unroll")                                                         \
    for (int mf = 0; mf < 8; ++mf)                                            \
        _Pragma("unroll")                                                     \
        for (int nj = 0; nj < 2; ++nj)                                        \
            acc[mf][(NHALF) * 2 + nj] = __builtin_amdgcn_mfma_f32_16x16x32_bf16( \
                af[mf], bfr[nj], acc[mf][(NHALF) * 2 + nj], 0, 0, 0);         \
    __builtin_amdgcn_s_setprio(0);                                            \
    __builtin_amdgcn_sched_barrier(0);                                        \
    if (DRAIN) { asm volatile("s_waitcnt vmcnt(8)" ::: "memory"); }           \
    asm volatile("" ::: "memory");                                            \
    __builtin_amdgcn_s_barrier();

__global__ __launch_bounds__(512) void gemm_qkv(
    const ushort_t* __restrict__ A, const ushort_t* __restrict__ BT,
    const float* __restrict__ bias,
    ushort_t* __restrict__ qbuf, ushort_t* __restrict__ kbuf,
    ushort_t* __restrict__ vTbuf) {
    __shared__ ushort_t lds[65536];  // 128 KiB
    const int t = threadIdx.x;
    const int w = t >> 6, lane = t & 63, lm = lane & 15, lq = lane >> 4;
    const int wm = (w >> 2) * 128, wn = (w & 3) * 64;
    const int mb = blockIdx.x * 256, nb = blockIdx.y * 256;

    const ushort_t* gA = A + (size_t)mb * HID;
    const ushort_t* gB = BT + (size_t)nb * HID;

    // staging source offsets (inverse of LDS slot swizzle): thread t, load j
    // covers slot j*512+t -> row r = slot>>2, chunk c = (slot&3)^((r>>1)&3)
    int soff[2];
#pragma unroll
    for (int j = 0; j < 2; ++j) {
        int r = j * 128 + (t >> 2);
        int c = (t & 3) ^ ((r >> 1) & 3);
        soff[j] = r * HID + c * 8;
    }

    f32x4 acc[8][4] = {};
    bf16x8 af[8], bfr[2];

    // prologue: stage T0 (both k-halves) + T1 kh0, drain, publish
    QSTAGE(gA, 0, 0, 0, 0) QSTAGE(gB, 1, 0, 0, 0)
    QSTAGE(gA, 0, 0, 1, 0) QSTAGE(gB, 1, 0, 1, 0)
    QSTAGE(gA, 0, 1, 0, 1) QSTAGE(gB, 1, 1, 0, 1)
    asm volatile("s_waitcnt vmcnt(0)" ::: "memory");
    __builtin_amdgcn_s_barrier();

#pragma unroll 1
    for (int i = 0; i < 16; ++i) {
        const int Tb = 2 * i + 1;
        const int T2 = (2 * i + 2) & 31, T3 = (2 * i + 3) & 31;
        QPHASE(0, 0, 0, 1, gA, 0, 1, 1, Tb, 0)
        QPHASE(0, 0, 1, 0, gB, 1, 1, 1, Tb, 1)
        QPHASE(0, 1, 0, 1, gA, 0, 0, 0, T2, 0)
        QPHASE(0, 1, 1, 0, gB, 1, 0, 0, T2, 1)
        QPHASE(1, 0, 0, 1, gA, 0, 0, 1, T2, 0)
        QPHASE(1, 0, 1, 0, gB, 1, 0, 1, T2, 1)
        QPHASE(1, 1, 0, 1, gA, 0, 1, 0, T3, 0)
        QPHASE(1, 1, 1, 0, gB, 1, 1, 0, T3, 1)
    }

    asm volatile("s_waitcnt vmcnt(0)" ::: "memory");  // drain tail stages

    const int sec = nb >> 11;
    if (sec < 2) {
        // q/k: direct scatter (coalesced in d across lm)
#pragma unroll
        for (int mf = 0; mf < 8; ++mf)
#pragma unroll
            for (int nf = 0; nf < 4; ++nf)
#pragma unroll
                for (int r = 0; r < 4; ++r) {
                    int m = mb + wm + mf * 16 + lq * 4 + r;
                    int c = nb + wn + nf * 16 + lm;
                    float val = acc[mf][nf][r] + bias[c];
                    int hh = (c >> 7) & 15;
                    int d = c & 127;
                    int b = m >> 11, s = m & 2047;
                    size_t bh = (size_t)(b * NH + hh);
                    ushort_t* dst = (sec == 0) ? qbuf : kbuf;
                    dst[(bh * SEQ + s) * HD + d] = f2bf(val);
                }
    } else {
        // v: transpose in LDS (two 128-col half passes), write vT coalesced
        __syncthreads();
        unsigned* T = (unsigned*)lds;  // [d(128)][132 uints]
        const int b = mb >> 11, sbase = mb & 2047;
        const int hv0 = (nb >> 7) - 32;
        const int dd = t & 127, sh = t >> 7;
#pragma unroll 1
        for (int ch = 0; ch < 2; ++ch) {
            if (((w >> 1) & 1) == ch) {  // waves with wn in this col-half
                const int cl = (w & 1) * 64;
#pragma unroll
                for (int nf = 0; nf < 4; ++nf) {
                    const int clc = cl + nf * 16 + lm;  // d 0..127
                    const float bb = bias[nb + ch * 128 + clc];
#pragma unroll
                    for (int mf = 0; mf < 8; ++mf) {
                        const int ml = wm + mf * 16 + lq * 4;  // s-local base
#pragma unroll
                        for (int r = 0; r < 4; r += 2) {
                            unsigned pk = (unsigned)f2bf(acc[mf][nf][r] + bb) |
                                          ((unsigned)f2bf(acc[mf][nf][r + 1] + bb) << 16);
                            T[clc * 132 + ((ml + r) >> 1)] = pk;
                        }
                    }
                }
            }
            __syncthreads();
            {
                ushort_t* vrow = vTbuf +
                    ((size_t)(b * NH + hv0 + ch) * HD + dd) * SEQ + sbase + sh * 64;
#pragma unroll
                for (int ii = 0; ii < 8; ++ii)
                    *(uint4*)(vrow + ii * 8) = *(const uint4*)&T[dd * 132 + sh * 32 + ii * 4];
            }
            __syncthreads();
        }
    }
}

// GEMM 2 (m97 structure kept: 512-block grid suits 128x128 tiles):
// out = attn(bf16) @ w_proj + b_proj -> fp32
__global__ __launch_bounds__(256) void gemm_proj(
    const ushort_t* __restrict__ A, const ushort_t* __restrict__ BT,
    const float* __restrict__ bias, float* __restrict__ out) {
    __shared__ ushort_t Abuf[128 * 64];
    __shared__ ushort_t Bbuf[128 * 64];
    ushort_t* At = Abuf;
    ushort_t* Bt = Bbuf;
    const int mb = blockIdx.x * 128;
    const int nb = blockIdx.y * 128;
    GEMM_KLOOP(A, BT)
#pragma unroll
    for (int mt = 0; mt < 4; ++mt)
#pragma unroll
        for (int nt = 0; nt < 4; ++nt)
#pragma unroll
            for (int r = 0; r < 4; ++r) {
                int m = mb + wm + mt * 16 + lq * 4 + r;
                int c = nb + wn + nt * 16 + lm;
                out[(size_t)m * HID + c] = acc[mt][nt][r] + bias[c];
            }
}

// ---------------------------------------------------------------------------
// Flash attention, S^T = K Q^T. Grid 1024. XCD-pinned block mapping:
//   bid = g*8 + (bh&7), g = (31-qt)*4 + (bh>>3)
// Double-buffered global_load_lds staging; one __syncthreads per iteration
// (drain lands after compute). + setprio (T5), defer-max (T13, THR=8).
// ---------------------------------------------------------------------------
__global__ __launch_bounds__(256) void attn_kernel(
    const ushort_t* __restrict__ qb, const ushort_t* __restrict__ kbuf,
    const ushort_t* __restrict__ vT, ushort_t* __restrict__ ob) {
    __shared__ ushort_t Ks[2][64 * 128];   // [key][d] swizzled 16B chunks
    __shared__ ushort_t Vs[2][128 * 64];   // [d][key] swizzled 16B chunks
    __shared__ ushort_t Ps[4][16 * 72];    // per-wave P, row stride 72

    const int bid = blockIdx.x;
    const int x = bid & 7, g = bid >> 3;
    const int qt = 31 - (g >> 2);
    const int bh = ((g & 3) << 3) | x;
    const int qbase = qt * 64;
    const int t = threadIdx.x, w = t >> 6, lane = t & 63;
    const int lm = lane & 15, lq = lane >> 4;

    const ushort_t* Qg = qb + (size_t)bh * SEQ * HD;
    const ushort_t* Kg = kbuf + (size_t)bh * SEQ * HD;
    const ushort_t* Vg = vT + (size_t)bh * HD * SEQ;

    const float LOG2E = 1.44269504f;
    const int h = bh & 15;
    const float slope2 = exp2f(-0.5f * (float)(h + 1)) * LOG2E;
    const float scale2 = (1.0f / 128.0f) * LOG2E;

    const int qg = qbase + w * 16 + lm;  // this lane's q row

    // Q fragments direct from global (B-operand layout)
    bf16x8 qf[4];
#pragma unroll
    for (int kc = 0; kc < 4; ++kc) {
        uint4 qv = *(const uint4*)(Qg + (size_t)qg * HD + kc * 32 + lq * 8);
        qf[kc] = __builtin_bit_cast(bf16x8, qv);
    }

    float foff[4][4];
#pragma unroll
    for (int mt = 0; mt < 4; ++mt)
#pragma unroll
        for (int r = 0; r < 4; ++r)
            foff[mt][r] = slope2 * (float)(mt * 16 + lq * 4 + r);

    // per-thread swizzled DMA source offsets
    int koffs[4], voffs[4];
#pragma unroll
    for (int i = 0; i < 4; ++i) {
        int ci = i * 256 + t;
        int kr = ci >> 4, ks = ci & 15;
        int kcg = (ks & 8) | ((ks & 7) ^ (kr & 7));
        koffs[i] = kr * HD + kcg * 8;
        int vr = ci >> 3, vs = ci & 7;
        int vcg = vs ^ (vr & 7);
        voffs[i] = vr * SEQ + vcg * 8;
    }

#define ATTN_STAGE(KT, BUF)                                                   \
    {                                                                         \
        const ushort_t* Kt_ = Kg + (size_t)(KT) * 64 * HD;                    \
        const ushort_t* Vt_ = Vg + (size_t)(KT) * 64;                         \
        _Pragma("unroll")                                                     \
        for (int i = 0; i < 4; ++i) {                                         \
            gl2lds16(Kt_ + koffs[i], Ks[BUF] + (i * 256 + w * 64) * 8);       \
            gl2lds16(Vt_ + voffs[i], Vs[BUF] + (i * 256 + w * 64) * 8);       \
        }                                                                     \
    }

    float mrow = -1e30f, lrow = 0.0f;
    f32x4 O[8] = {};
    const int nkt = qt + 1;

    // prologue: stage tile 0, drain, sync
    ATTN_STAGE(0, 0)
    __syncthreads();

    for (int kt = 0; kt < nkt; ++kt) {
        const int cur = kt & 1;
        if (kt + 1 < nkt) ATTN_STAGE(kt + 1, cur ^ 1)

        // S^T = K Q^T : per wave 64 keys x 16 q
        f32x4 sacc[4] = {};
        __builtin_amdgcn_s_setprio(1);
#pragma unroll
        for (int kc = 0; kc < 4; ++kc) {
            const int slot = ((kc * 4 + lq) & 8) | (((kc * 4 + lq) & 7) ^ (lm & 7));
#pragma unroll
            for (int mt = 0; mt < 4; ++mt) {
                bf16x8 bk = *(const bf16x8*)&Ks[cur][((mt * 16 + lm) * 16 + slot) * 8];
                sacc[mt] = __builtin_amdgcn_mfma_f32_16x16x32_bf16(bk, qf[kc], sacc[mt], 0, 0, 0);
            }
        }
        __builtin_amdgcn_s_setprio(0);

        // scores (log2 domain); mask only on the diagonal tile
        const float sbase = slope2 * (float)(kt * 64 - qg);
        float sc[4][4];
        if (kt == qt) {
#pragma unroll
            for (int mt = 0; mt < 4; ++mt)
#pragma unroll
                for (int r = 0; r < 4; ++r) {
                    float s = sacc[mt][r] * scale2 + (sbase + foff[mt][r]);
                    sc[mt][r] = (kt * 64 + mt * 16 + lq * 4 + r <= qg) ? s : -3e38f;
                }
        } else {
#pragma unroll
            for (int mt = 0; mt < 4; ++mt)
#pragma unroll
                for (int r = 0; r < 4; ++r)
                    sc[mt][r] = sacc[mt][r] * scale2 + (sbase + foff[mt][r]);
        }

        // row max
        float tm = sc[0][0];
#pragma unroll
        for (int mt = 0; mt < 4; ++mt)
#pragma unroll
            for (int r = 0; r < 4; ++r) tm = fmaxf(tm, sc[mt][r]);
        tm = fmaxf(tm, __shfl_xor(tm, 16));
        tm = fmaxf(tm, __shfl_xor(tm, 32));

        // defer-max (T13)
        const bool noresc = __all(tm <= mrow + 8.0f) && (kt > 0);
        float mnew, alpha;
        if (noresc) {
            mnew = mrow;
            alpha = 1.0f;
        } else {
            mnew = fmaxf(mrow, tm);
            alpha = __builtin_amdgcn_exp2f(mrow - mnew);
        }
        mrow = mnew;

        // p = exp2(sc - m) -> Ps[q][key], sum
        float psum = 0.0f;
#pragma unroll
        for (int mt = 0; mt < 4; ++mt) {
            float p0 = __builtin_amdgcn_exp2f(sc[mt][0] - mnew);
            float p1 = __builtin_amdgcn_exp2f(sc[mt][1] - mnew);
            float p2 = __builtin_amdgcn_exp2f(sc[mt][2] - mnew);
            float p3 = __builtin_amdgcn_exp2f(sc[mt][3] - mnew);
            psum += (p0 + p1) + (p2 + p3);
            uint2 wv;
            wv.x = ((unsigned)f2bf(p1) << 16) | f2bf(p0);
            wv.y = ((unsigned)f2bf(p3) << 16) | f2bf(p2);
            *(uint2*)&Ps[w][lm * 72 + mt * 16 + lq * 4] = wv;
        }
        psum += __shfl_xor(psum, 16);
        psum += __shfl_xor(psum, 32);
        lrow = lrow * alpha + psum;

        if (!noresc) {
            float av[4];
#pragma unroll
            for (int r = 0; r < 4; ++r) av[r] = __shfl(alpha, lq * 4 + r);
#pragma unroll
            for (int nt = 0; nt < 8; ++nt)
#pragma unroll
                for (int r = 0; r < 4; ++r) O[nt][r] *= av[r];
        }

        // PV: A = P (q=lane&15), B = V^T (swizzled)
        asm volatile("s_waitcnt lgkmcnt(0)" ::: "memory");
        __builtin_amdgcn_s_setprio(1);
#pragma unroll
        for (int kc2 = 0; kc2 < 2; ++kc2) {
            bf16x8 ap = *(const bf16x8*)&Ps[w][lm * 72 + kc2 * 32 + lq * 8];
            const int slot = (kc2 * 4 + lq) ^ (lm & 7);
#pragma unroll
            for (int nt = 0; nt < 8; ++nt) {
                bf16x8 bv = *(const bf16x8*)&Vs[cur][((nt * 16 + lm) * 8 + slot) * 8];
                O[nt] = __builtin_amdgcn_mfma_f32_16x16x32_bf16(ap, bv, O[nt], 0, 0, 0);
            }
        }
        __builtin_amdgcn_s_setprio(0);

        __syncthreads();
    }

    // epilogue
    float lb[4];
#pragma unroll
    for (int r = 0; r < 4; ++r)
        lb[r] = __builtin_amdgcn_rcpf(__shfl(lrow, lq * 4 + r));
    const int b = bh >> 4;
#pragma unroll
    for (int nt = 0; nt < 8; ++nt)
#pragma unroll
        for (int r = 0; r < 4; ++r) {
            int s = qbase + w * 16 + lq * 4 + r;
            int d = nt * 16 + lm;
            ob[((size_t)(b * SEQ + s)) * HID + h * HD + d] = f2bf(O[nt][r] * lb[r]);
        }
#undef ATTN_STAGE
}

// ---------------------------------------------------------------------------
extern "C" void kernel_launch(void* const* d_in, const int* in_sizes, int n_in,
                              void* d_out, int out_size, void* d_ws, size_t ws_size,
                              hipStream_t stream) {
    const float* hidden = (const float*)d_in[0];
    const float* w_qkv = (const float*)d_in[1];
    const float* b_qkv = (const float*)d_in[2];
    const float* w_proj = (const float*)d_in[3];
    const float* b_proj = (const float*)d_in[4];
    float* out = (float*)d_out;

    char* ws = (char*)d_ws;
    size_t off = 0;
    ushort_t* wqkvT = (ushort_t*)(ws + off); off += (size_t)NQKV * HID * 2;
    ushort_t* wprojT = (ushort_t*)(ws + off); off += (size_t)HID * HID * 2;
    ushort_t* hbf = (ushort_t*)(ws + off); off += (size_t)BATCH * SEQ * HID * 2;
    ushort_t* qw = (ushort_t*)(ws + off); off += (size_t)BATCH * NH * SEQ * HD * 2;
    ushort_t* kw = (ushort_t*)(ws + off); off += (size_t)BATCH * NH * SEQ * HD * 2;
    ushort_t* vTw = (ushort_t*)(ws + off); off += (size_t)BATCH * NH * SEQ * HD * 2;
    ushort_t* attnw = (ushort_t*)(ws + off); off += (size_t)BATCH * SEQ * HID * 2;

    to_bf16<<<dim3(BATCH * SEQ * HID / 8 / 256), 256, 0, stream>>>(
        hidden, hbf, BATCH * SEQ * HID / 8);
    transpose_to_bf16<<<dim3(NQKV / 32, HID / 32), dim3(32, 8), 0, stream>>>(
        w_qkv, wqkvT, HID, NQKV);
    transpose_to_bf16<<<dim3(HID / 32, HID / 32), dim3(32, 8), 0, stream>>>(
        w_proj, wprojT, HID, HID);

    gemm_qkv<<<dim3(BATCH * SEQ / 256, NQKV / 256), 512, 0, stream>>>(
        hbf, wqkvT, b_qkv, qw, kw, vTw);

    attn_kernel<<<dim3(BATCH * NH * 32), 256, 0, stream>>>(qw, kw, vTw, attnw);

    gemm_proj<<<dim3(BATCH * SEQ / 128, HID / 128), 256, 0, stream>>>(
        attnw, wprojT, b_proj, out);
}

// Round 5
// 365.619 us; speedup vs baseline: 1.0319x; 1.0319x over previous
//
#include <hip/hip_runtime.h>
#include <hip/hip_bf16.h>

typedef short bf16x8 __attribute__((ext_vector_type(8)));
typedef float f32x4 __attribute__((ext_vector_type(4)));
typedef unsigned short ushort_t;

#define NH 16
#define HD 128
#define SEQ 2048
#define HID 2048
#define NQKV 6144
#define BATCH 2

__device__ __forceinline__ ushort_t f2bf(float x) {
    unsigned u = __builtin_bit_cast(unsigned, x);
    u = (u + 0x7fffu + ((u >> 16) & 1u)) >> 16;
    return (ushort_t)u;
}

// async global->LDS, 16B per lane. LDS dest = wave-uniform base + lane*16.
__device__ __forceinline__ void gl2lds16(const ushort_t* g, ushort_t* l) {
    __builtin_amdgcn_global_load_lds(
        (__attribute__((address_space(1))) void*)(g),
        (__attribute__((address_space(3))) void*)(l), 16, 0, 0);
}

// ---------------------------------------------------------------------------
// Fused prep (one launch instead of three):
//   blocks [0, 12288):      transpose+cast w_qkv  [HID][NQKV] -> [NQKV][HID]
//   blocks [12288, 16384):  fp32->bf16 hidden states (8 elems/thread)
//   blocks [16384, 20480):  transpose+cast w_proj [HID][HID] -> [HID][HID]
// All three are independent, memory-bound; fusing removes 2 launch gaps and
// lets them overlap on-chip.
// ---------------------------------------------------------------------------
__global__ __launch_bounds__(256) void prep_fused(
    const float* __restrict__ hidden, ushort_t* __restrict__ hbf,
    const float* __restrict__ wqkv, ushort_t* __restrict__ wqkvT,
    const float* __restrict__ wproj, ushort_t* __restrict__ wprojT) {
    const int bid = blockIdx.x;
    const int t = threadIdx.x;
    if (bid >= 12288 && bid < 16384) {
        // hidden fp32 -> bf16, 8 elems/thread
        int i = (bid - 12288) * 256 + t;
        float4 a0 = *(const float4*)(hidden + (size_t)i * 8);
        float4 a1 = *(const float4*)(hidden + (size_t)i * 8 + 4);
        union { ushort_t u[8]; uint4 v; } p;
        p.u[0]=f2bf(a0.x); p.u[1]=f2bf(a0.y); p.u[2]=f2bf(a0.z); p.u[3]=f2bf(a0.w);
        p.u[4]=f2bf(a1.x); p.u[5]=f2bf(a1.y); p.u[6]=f2bf(a1.z); p.u[7]=f2bf(a1.w);
        *(uint4*)(hbf + (size_t)i * 8) = p.v;
        return;
    }
    // transpose path: w [K=HID][N] -> wT [N][K]
    const float* w;
    ushort_t* wT;
    int N, bx, by;
    if (bid < 12288) {
        w = wqkv; wT = wqkvT; N = NQKV;
        bx = bid % 192; by = bid / 192;          // N/32 x K/32
    } else {
        int b2 = bid - 16384;
        w = wproj; wT = wprojT; N = HID;
        bx = b2 % 64; by = b2 / 64;
    }
    __shared__ float tile[32][33];
    const int nb = bx * 32, kb = by * 32;
    const int tx = t & 31, ty = t >> 5;          // 32 x 8
#pragma unroll
    for (int i = 0; i < 4; ++i) {
        int k = kb + ty + i * 8;
        tile[ty + i * 8][tx] = w[(size_t)k * N + nb + tx];
    }
    __syncthreads();
#pragma unroll
    for (int i = 0; i < 4; ++i) {
        int n = nb + ty + i * 8;
        wT[(size_t)n * HID + kb + tx] = f2bf(tile[tx][ty + i * 8]);
    }
}

// ---------------------------------------------------------------------------
// m97-style GEMM core: 128x128 tile, BK=64, global_load_lds(16B) staging with
// XOR-swizzled chunk order. LDS[r][slot s] holds global k-chunk s^(r&7).
// (8-phase 256^2 was tried in R3/R4: per-block +24% but 384-block grid at
// 1 block/CU quantizes to 75% -> net loss. This structure is the ceiling
// for this grid shape.)
// ---------------------------------------------------------------------------
#define GEMM_KLOOP(A_, BT_)                                                     \
    const int t = threadIdx.x;                                                  \
    const int w = t >> 6, lane = t & 63, lm = lane & 15, lq = lane >> 4;        \
    const int wm = (w >> 1) * 64, wn = (w & 1) * 64;                            \
    const int lrow = lane >> 3, lsw = (lane & 7) ^ lrow;                        \
    f32x4 acc[4][4] = {};                                                       \
    const ushort_t* gA = A_ + (size_t)(mb + w * 32 + lrow) * HID + lsw * 8;     \
    const ushort_t* gB = BT_ + (size_t)(nb + w * 32 + lrow) * HID + lsw * 8;    \
    for (int kb = 0; kb < HID; kb += 64) {                                      \
        __syncthreads();                                                        \
        _Pragma("unroll")                                                       \
        for (int c = 0; c < 4; ++c) {                                           \
            gl2lds16(gA + (size_t)c * 8 * HID + kb, At + (w * 256 + c * 64) * 8); \
            gl2lds16(gB + (size_t)c * 8 * HID + kb, Bt + (w * 256 + c * 64) * 8); \
        }                                                                       \
        __syncthreads();                                                        \
        _Pragma("unroll")                                                       \
        for (int kc = 0; kc < 2; ++kc) {                                        \
            const int slot = (kc * 4 + lq) ^ (lm & 7);                          \
            bf16x8 af[4], bfr[4];                                               \
            _Pragma("unroll")                                                   \
            for (int mt = 0; mt < 4; ++mt)                                      \
                af[mt] = ((const bf16x8*)At)[(wm + mt * 16 + lm) * 8 + slot];   \
            _Pragma("unroll")                                                   \
            for (int nt = 0; nt < 4; ++nt)                                      \
                bfr[nt] = ((const bf16x8*)Bt)[(wn + nt * 16 + lm) * 8 + slot];  \
            _Pragma("unroll")                                                   \
            for (int mt = 0; mt < 4; ++mt)                                      \
                _Pragma("unroll")                                               \
                for (int nt = 0; nt < 4; ++nt)                                  \
                    acc[mt][nt] = __builtin_amdgcn_mfma_f32_16x16x32_bf16(      \
                        af[mt], bfr[nt], acc[mt][nt], 0, 0, 0);                 \
        }                                                                       \
    }

// ---------------------------------------------------------------------------
// GEMM 1: qkv = hidden(bf16) @ w_qkv + b_qkv
// q,k -> [B,nh,S,hd]; v -> vT [B,nh,hd,S] via in-LDS transpose (tile = 128 s
// x one head's 128 d), coalesced 16B writes.
// ---------------------------------------------------------------------------
__global__ __launch_bounds__(256) void gemm_qkv(
    const ushort_t* __restrict__ A, const ushort_t* __restrict__ BT,
    const float* __restrict__ bias,
    ushort_t* __restrict__ qbuf, ushort_t* __restrict__ kbuf,
    ushort_t* __restrict__ vTbuf) {
    __shared__ unsigned shbuf[128 * 68];  // 34KB: staging (32KB) / transpose T
    ushort_t* At = (ushort_t*)shbuf;
    ushort_t* Bt = At + 128 * 64;
    const int mb = blockIdx.x * 128;
    const int nb = blockIdx.y * 128;
    GEMM_KLOOP(A, BT)

    const int sec = nb >> 11;
    if (sec < 2) {
        // q/k: direct scatter (coalesced in d across lm)
#pragma unroll
        for (int mt = 0; mt < 4; ++mt)
#pragma unroll
            for (int nt = 0; nt < 4; ++nt)
#pragma unroll
                for (int r = 0; r < 4; ++r) {
                    int m = mb + wm + mt * 16 + lq * 4 + r;
                    int c = nb + wn + nt * 16 + lm;
                    float val = acc[mt][nt][r] + bias[c];
                    int h = (c >> 7) & 15;
                    int d = c & 127;
                    int b = m >> 11, s = m & 2047;
                    size_t bh = (size_t)(b * NH + h);
                    ushort_t* dst = (sec == 0) ? qbuf : kbuf;
                    dst[(bh * SEQ + s) * HD + d] = f2bf(val);
                }
    } else {
        // v: transpose in LDS, write vT[bh][d][s] coalesced
        __syncthreads();  // all waves done reading staging LDS
        unsigned* T = shbuf;  // [c(128)][68 uints], uint idx = c*68 + m/2
#pragma unroll
        for (int mt = 0; mt < 4; ++mt)
#pragma unroll
            for (int nt = 0; nt < 4; ++nt) {
                const int cl = wn + nt * 16 + lm;       // d 0..127
                const int ml = wm + mt * 16 + lq * 4;   // s-local base
                const float bb = bias[nb + cl];
#pragma unroll
                for (int r = 0; r < 4; r += 2) {
                    unsigned pk = (unsigned)f2bf(acc[mt][nt][r] + bb) |
                                  ((unsigned)f2bf(acc[mt][nt][r + 1] + bb) << 16);
                    T[cl * 68 + ((ml + r) >> 1)] = pk;
                }
            }
        __syncthreads();
        const int d = t & 127, sh = t >> 7;
        const int b = mb >> 11, sbase = mb & 2047;
        const int hv = (nb >> 7) - 32;
        ushort_t* vrow = vTbuf + ((size_t)(b * NH + hv) * HD + d) * SEQ + sbase + sh * 64;
#pragma unroll
        for (int i = 0; i < 8; ++i)
            *(uint4*)(vrow + i * 8) = *(const uint4*)&T[d * 68 + sh * 32 + i * 4];
    }
}

// GEMM 2: out = attn(bf16) @ w_proj + b_proj -> fp32
__global__ __launch_bounds__(256) void gemm_proj(
    const ushort_t* __restrict__ A, const ushort_t* __restrict__ BT,
    const float* __restrict__ bias, float* __restrict__ out) {
    __shared__ ushort_t Abuf[128 * 64];
    __shared__ ushort_t Bbuf[128 * 64];
    ushort_t* At = Abuf;
    ushort_t* Bt = Bbuf;
    const int mb = blockIdx.x * 128;
    const int nb = blockIdx.y * 128;
    GEMM_KLOOP(A, BT)
#pragma unroll
    for (int mt = 0; mt < 4; ++mt)
#pragma unroll
        for (int nt = 0; nt < 4; ++nt)
#pragma unroll
            for (int r = 0; r < 4; ++r) {
                int m = mb + wm + mt * 16 + lq * 4 + r;
                int c = nb + wn + nt * 16 + lm;
                out[(size_t)m * HID + c] = acc[mt][nt][r] + bias[c];
            }
}

// ---------------------------------------------------------------------------
// Flash attention, S^T = K Q^T. Grid 1024. XCD-pinned block mapping:
//   bid = g*8 + (bh&7), g = (31-qt)*4 + (bh>>3)
// Double-buffered global_load_lds staging; one __syncthreads per iteration
// (drain lands after compute). + setprio (T5), defer-max (T13, THR=8).
// ---------------------------------------------------------------------------
__global__ __launch_bounds__(256) void attn_kernel(
    const ushort_t* __restrict__ qb, const ushort_t* __restrict__ kbuf,
    const ushort_t* __restrict__ vT, ushort_t* __restrict__ ob) {
    __shared__ ushort_t Ks[2][64 * 128];   // [key][d] swizzled 16B chunks
    __shared__ ushort_t Vs[2][128 * 64];   // [d][key] swizzled 16B chunks
    __shared__ ushort_t Ps[4][16 * 72];    // per-wave P, row stride 72

    const int bid = blockIdx.x;
    const int x = bid & 7, g = bid >> 3;
    const int qt = 31 - (g >> 2);
    const int bh = ((g & 3) << 3) | x;
    const int qbase = qt * 64;
    const int t = threadIdx.x, w = t >> 6, lane = t & 63;
    const int lm = lane & 15, lq = lane >> 4;

    const ushort_t* Qg = qb + (size_t)bh * SEQ * HD;
    const ushort_t* Kg = kbuf + (size_t)bh * SEQ * HD;
    const ushort_t* Vg = vT + (size_t)bh * HD * SEQ;

    const float LOG2E = 1.44269504f;
    const int h = bh & 15;
    const float slope2 = exp2f(-0.5f * (float)(h + 1)) * LOG2E;
    const float scale2 = (1.0f / 128.0f) * LOG2E;

    const int qg = qbase + w * 16 + lm;  // this lane's q row

    // Q fragments direct from global (B-operand layout)
    bf16x8 qf[4];
#pragma unroll
    for (int kc = 0; kc < 4; ++kc) {
        uint4 qv = *(const uint4*)(Qg + (size_t)qg * HD + kc * 32 + lq * 8);
        qf[kc] = __builtin_bit_cast(bf16x8, qv);
    }

    float foff[4][4];
#pragma unroll
    for (int mt = 0; mt < 4; ++mt)
#pragma unroll
        for (int r = 0; r < 4; ++r)
            foff[mt][r] = slope2 * (float)(mt * 16 + lq * 4 + r);

    // per-thread swizzled DMA source offsets
    int koffs[4], voffs[4];
#pragma unroll
    for (int i = 0; i < 4; ++i) {
        int ci = i * 256 + t;
        int kr = ci >> 4, ks = ci & 15;
        int kcg = (ks & 8) | ((ks & 7) ^ (kr & 7));
        koffs[i] = kr * HD + kcg * 8;
        int vr = ci >> 3, vs = ci & 7;
        int vcg = vs ^ (vr & 7);
        voffs[i] = vr * SEQ + vcg * 8;
    }

#define ATTN_STAGE(KT, BUF)                                                   \
    {                                                                         \
        const ushort_t* Kt_ = Kg + (size_t)(KT) * 64 * HD;                    \
        const ushort_t* Vt_ = Vg + (size_t)(KT) * 64;                         \
        _Pragma("unroll")                                                     \
        for (int i = 0; i < 4; ++i) {                                         \
            gl2lds16(Kt_ + koffs[i], Ks[BUF] + (i * 256 + w * 64) * 8);       \
            gl2lds16(Vt_ + voffs[i], Vs[BUF] + (i * 256 + w * 64) * 8);       \
        }                                                                     \
    }

    float mrow = -1e30f, lrow = 0.0f;
    f32x4 O[8] = {};
    const int nkt = qt + 1;

    // prologue: stage tile 0, drain, sync
    ATTN_STAGE(0, 0)
    __syncthreads();

    for (int kt = 0; kt < nkt; ++kt) {
        const int cur = kt & 1;
        if (kt + 1 < nkt) ATTN_STAGE(kt + 1, cur ^ 1)

        // S^T = K Q^T : per wave 64 keys x 16 q
        f32x4 sacc[4] = {};
        __builtin_amdgcn_s_setprio(1);
#pragma unroll
        for (int kc = 0; kc < 4; ++kc) {
            const int slot = ((kc * 4 + lq) & 8) | (((kc * 4 + lq) & 7) ^ (lm & 7));
#pragma unroll
            for (int mt = 0; mt < 4; ++mt) {
                bf16x8 bk = *(const bf16x8*)&Ks[cur][((mt * 16 + lm) * 16 + slot) * 8];
                sacc[mt] = __builtin_amdgcn_mfma_f32_16x16x32_bf16(bk, qf[kc], sacc[mt], 0, 0, 0);
            }
        }
        __builtin_amdgcn_s_setprio(0);

        // scores (log2 domain); mask only on the diagonal tile
        const float sbase = slope2 * (float)(kt * 64 - qg);
        float sc[4][4];
        if (kt == qt) {
#pragma unroll
            for (int mt = 0; mt < 4; ++mt)
#pragma unroll
                for (int r = 0; r < 4; ++r) {
                    float s = sacc[mt][r] * scale2 + (sbase + foff[mt][r]);
                    sc[mt][r] = (kt * 64 + mt * 16 + lq * 4 + r <= qg) ? s : -3e38f;
                }
        } else {
#pragma unroll
            for (int mt = 0; mt < 4; ++mt)
#pragma unroll
                for (int r = 0; r < 4; ++r)
                    sc[mt][r] = sacc[mt][r] * scale2 + (sbase + foff[mt][r]);
        }

        // row max
        float tm = sc[0][0];
#pragma unroll
        for (int mt = 0; mt < 4; ++mt)
#pragma unroll
            for (int r = 0; r < 4; ++r) tm = fmaxf(tm, sc[mt][r]);
        tm = fmaxf(tm, __shfl_xor(tm, 16));
        tm = fmaxf(tm, __shfl_xor(tm, 32));

        // defer-max (T13)
        const bool noresc = __all(tm <= mrow + 8.0f) && (kt > 0);
        float mnew, alpha;
        if (noresc) {
            mnew = mrow;
            alpha = 1.0f;
        } else {
            mnew = fmaxf(mrow, tm);
            alpha = __builtin_amdgcn_exp2f(mrow - mnew);
        }
        mrow = mnew;

        // p = exp2(sc - m) -> Ps[q][key], sum
        float psum = 0.0f;
#pragma unroll
        for (int mt = 0; mt < 4; ++mt) {
            float p0 = __builtin_amdgcn_exp2f(sc[mt][0] - mnew);
            float p1 = __builtin_amdgcn_exp2f(sc[mt][1] - mnew);
            float p2 = __builtin_amdgcn_exp2f(sc[mt][2] - mnew);
            float p3 = __builtin_amdgcn_exp2f(sc[mt][3] - mnew);
            psum += (p0 + p1) + (p2 + p3);
            uint2 wv;
            wv.x = ((unsigned)f2bf(p1) << 16) | f2bf(p0);
            wv.y = ((unsigned)f2bf(p3) << 16) | f2bf(p2);
            *(uint2*)&Ps[w][lm * 72 + mt * 16 + lq * 4] = wv;
        }
        psum += __shfl_xor(psum, 16);
        psum += __shfl_xor(psum, 32);
        lrow = lrow * alpha + psum;

        if (!noresc) {
            float av[4];
#pragma unroll
            for (int r = 0; r < 4; ++r) av[r] = __shfl(alpha, lq * 4 + r);
#pragma unroll
            for (int nt = 0; nt < 8; ++nt)
#pragma unroll
                for (int r = 0; r < 4; ++r) O[nt][r] *= av[r];
        }

        // PV: A = P (q=lane&15), B = V^T (swizzled)
        asm volatile("s_waitcnt lgkmcnt(0)" ::: "memory");
        __builtin_amdgcn_s_setprio(1);
#pragma unroll
        for (int kc2 = 0; kc2 < 2; ++kc2) {
            bf16x8 ap = *(const bf16x8*)&Ps[w][lm * 72 + kc2 * 32 + lq * 8];
            const int slot = (kc2 * 4 + lq) ^ (lm & 7);
#pragma unroll
            for (int nt = 0; nt < 8; ++nt) {
                bf16x8 bv = *(const bf16x8*)&Vs[cur][((nt * 16 + lm) * 8 + slot) * 8];
                O[nt] = __builtin_amdgcn_mfma_f32_16x16x32_bf16(ap, bv, O[nt], 0, 0, 0);
            }
        }
        __builtin_amdgcn_s_setprio(0);

        __syncthreads();
    }

    // epilogue
    float lb[4];
#pragma unroll
    for (int r = 0; r < 4; ++r)
        lb[r] = __builtin_amdgcn_rcpf(__shfl(lrow, lq * 4 + r));
    const int b = bh >> 4;
#pragma unroll
    for (int nt = 0; nt < 8; ++nt)
#pragma unroll
        for (int r = 0; r < 4; ++r) {
            int s = qbase + w * 16 + lq * 4 + r;
            int d = nt * 16 + lm;
            ob[((size_t)(b * SEQ + s)) * HID + h * HD + d] = f2bf(O[nt][r] * lb[r]);
        }
#undef ATTN_STAGE
}

// ---------------------------------------------------------------------------
extern "C" void kernel_launch(void* const* d_in, const int* in_sizes, int n_in,
                              void* d_out, int out_size, void* d_ws, size_t ws_size,
                              hipStream_t stream) {
    const float* hidden = (const float*)d_in[0];
    const float* w_qkv = (const float*)d_in[1];
    const float* b_qkv = (const float*)d_in[2];
    const float* w_proj = (const float*)d_in[3];
    const float* b_proj = (const float*)d_in[4];
    float* out = (float*)d_out;

    char* ws = (char*)d_ws;
    size_t off = 0;
    ushort_t* wqkvT = (ushort_t*)(ws + off); off += (size_t)NQKV * HID * 2;
    ushort_t* wprojT = (ushort_t*)(ws + off); off += (size_t)HID * HID * 2;
    ushort_t* hbf = (ushort_t*)(ws + off); off += (size_t)BATCH * SEQ * HID * 2;
    ushort_t* qw = (ushort_t*)(ws + off); off += (size_t)BATCH * NH * SEQ * HD * 2;
    ushort_t* kw = (ushort_t*)(ws + off); off += (size_t)BATCH * NH * SEQ * HD * 2;
    ushort_t* vTw = (ushort_t*)(ws + off); off += (size_t)BATCH * NH * SEQ * HD * 2;
    ushort_t* attnw = (ushort_t*)(ws + off); off += (size_t)BATCH * SEQ * HID * 2;

    // fused prep: wqkv-T (12288 blocks) + hidden cast (4096) + wproj-T (4096)
    prep_fused<<<dim3(20480), 256, 0, stream>>>(
        hidden, hbf, w_qkv, wqkvT, w_proj, wprojT);

    gemm_qkv<<<dim3(BATCH * SEQ / 128, NQKV / 128), 256, 0, stream>>>(
        hbf, wqkvT, b_qkv, qw, kw, vTw);

    attn_kernel<<<dim3(BATCH * NH * 32), 256, 0, stream>>>(qw, kw, vTw, attnw);

    gemm_proj<<<dim3(BATCH * SEQ / 128, HID / 128), 256, 0, stream>>>(
        attnw, wprojT, b_proj, out);
}

// Round 6
// 365.009 us; speedup vs baseline: 1.0336x; 1.0017x over previous
//
#include <hip/hip_runtime.h>
#include <hip/hip_bf16.h>

typedef short bf16x8 __attribute__((ext_vector_type(8)));
typedef float f32x4 __attribute__((ext_vector_type(4)));
typedef unsigned short ushort_t;

#define NH 16
#define HD 128
#define SEQ 2048
#define HID 2048
#define NQKV 6144
#define BATCH 2

__device__ __forceinline__ ushort_t f2bf(float x) {
    unsigned u = __builtin_bit_cast(unsigned, x);
    u = (u + 0x7fffu + ((u >> 16) & 1u)) >> 16;
    return (ushort_t)u;
}

// async global->LDS, 16B per lane. LDS dest = wave-uniform base + lane*16.
__device__ __forceinline__ void gl2lds16(const ushort_t* g, ushort_t* l) {
    __builtin_amdgcn_global_load_lds(
        (__attribute__((address_space(1))) void*)(g),
        (__attribute__((address_space(3))) void*)(l), 16, 0, 0);
}

// ---------------------------------------------------------------------------
// Fused prep (one launch):
//   blocks [0, 12288):      transpose+cast w_qkv  [HID][NQKV] -> [NQKV][HID]
//   blocks [12288, 16384):  fp32->bf16 hidden states (8 elems/thread)
//   blocks [16384, 20480):  transpose+cast w_proj [HID][HID] -> [HID][HID]
// ---------------------------------------------------------------------------
__global__ __launch_bounds__(256) void prep_fused(
    const float* __restrict__ hidden, ushort_t* __restrict__ hbf,
    const float* __restrict__ wqkv, ushort_t* __restrict__ wqkvT,
    const float* __restrict__ wproj, ushort_t* __restrict__ wprojT) {
    const int bid = blockIdx.x;
    const int t = threadIdx.x;
    if (bid >= 12288 && bid < 16384) {
        int i = (bid - 12288) * 256 + t;
        float4 a0 = *(const float4*)(hidden + (size_t)i * 8);
        float4 a1 = *(const float4*)(hidden + (size_t)i * 8 + 4);
        union { ushort_t u[8]; uint4 v; } p;
        p.u[0]=f2bf(a0.x); p.u[1]=f2bf(a0.y); p.u[2]=f2bf(a0.z); p.u[3]=f2bf(a0.w);
        p.u[4]=f2bf(a1.x); p.u[5]=f2bf(a1.y); p.u[6]=f2bf(a1.z); p.u[7]=f2bf(a1.w);
        *(uint4*)(hbf + (size_t)i * 8) = p.v;
        return;
    }
    const float* w;
    ushort_t* wT;
    int N, bx, by;
    if (bid < 12288) {
        w = wqkv; wT = wqkvT; N = NQKV;
        bx = bid % 192; by = bid / 192;
    } else {
        int b2 = bid - 16384;
        w = wproj; wT = wprojT; N = HID;
        bx = b2 % 64; by = b2 / 64;
    }
    __shared__ float tile[32][33];
    const int nb = bx * 32, kb = by * 32;
    const int tx = t & 31, ty = t >> 5;
#pragma unroll
    for (int i = 0; i < 4; ++i) {
        int k = kb + ty + i * 8;
        tile[ty + i * 8][tx] = w[(size_t)k * N + nb + tx];
    }
    __syncthreads();
#pragma unroll
    for (int i = 0; i < 4; ++i) {
        int n = nb + ty + i * 8;
        wT[(size_t)n * HID + kb + tx] = f2bf(tile[tx][ty + i * 8]);
    }
}

// ---------------------------------------------------------------------------
// m97-style GEMM core (kept for gemm_proj): 128x128 tile, BK=64.
// ---------------------------------------------------------------------------
#define GEMM_KLOOP(A_, BT_)                                                     \
    const int t = threadIdx.x;                                                  \
    const int w = t >> 6, lane = t & 63, lm = lane & 15, lq = lane >> 4;        \
    const int wm = (w >> 1) * 64, wn = (w & 1) * 64;                            \
    const int lrow = lane >> 3, lsw = (lane & 7) ^ lrow;                        \
    f32x4 acc[4][4] = {};                                                       \
    const ushort_t* gA = A_ + (size_t)(mb + w * 32 + lrow) * HID + lsw * 8;     \
    const ushort_t* gB = BT_ + (size_t)(nb + w * 32 + lrow) * HID + lsw * 8;    \
    for (int kb = 0; kb < HID; kb += 64) {                                      \
        __syncthreads();                                                        \
        _Pragma("unroll")                                                       \
        for (int c = 0; c < 4; ++c) {                                           \
            gl2lds16(gA + (size_t)c * 8 * HID + kb, At + (w * 256 + c * 64) * 8); \
            gl2lds16(gB + (size_t)c * 8 * HID + kb, Bt + (w * 256 + c * 64) * 8); \
        }                                                                       \
        __syncthreads();                                                        \
        _Pragma("unroll")                                                       \
        for (int kc = 0; kc < 2; ++kc) {                                        \
            const int slot = (kc * 4 + lq) ^ (lm & 7);                          \
            bf16x8 af[4], bfr[4];                                               \
            _Pragma("unroll")                                                   \
            for (int mt = 0; mt < 4; ++mt)                                      \
                af[mt] = ((const bf16x8*)At)[(wm + mt * 16 + lm) * 8 + slot];   \
            _Pragma("unroll")                                                   \
            for (int nt = 0; nt < 4; ++nt)                                      \
                bfr[nt] = ((const bf16x8*)Bt)[(wn + nt * 16 + lm) * 8 + slot];  \
            _Pragma("unroll")                                                   \
            for (int mt = 0; mt < 4; ++mt)                                      \
                _Pragma("unroll")                                               \
                for (int nt = 0; nt < 4; ++nt)                                  \
                    acc[mt][nt] = __builtin_amdgcn_mfma_f32_16x16x32_bf16(      \
                        af[mt], bfr[nt], acc[mt][nt], 0, 0, 0);                 \
        }                                                                       \
    }

// ---------------------------------------------------------------------------
// GEMM 1: 4-phase 256x128 pipelined template (T3+T4+T5, R4 schedule with
// quantization-clean geometry): grid 16x48 = 768 blocks = 3 clean rounds
// @1 block/CU. 512 thr = 8 waves (4M x 2N), per-wave C = 64x64 (4x4 frags).
// LDS 96KB: A units (256rx32k, 16KB) at (buf*2+kh)*8192; B units (128rx32k,
// 8KB) at 32768+(buf*2+kh)*4096. Unit slot = r*4 + (c ^ ((r>>1)&3)) (16B
// chunks; inverse swizzle on gl2lds global source).
// Per iteration (2 K-tiles: Ta=2i buf0, Tb=2i+1 buf1), 4 phases of 16 MFMA:
//  ph1: stage A+B[b1][kh1]<-Tb ; compute buf0 kh0
//  ph2: stage A+B[b0][kh0]<-T2 ; compute buf0 kh1 ; vmcnt(3)
//  ph3: stage A+B[b0][kh1]<-T2 ; compute buf1 kh0
//  ph4: stage A+B[b1][kh0]<-T3 ; compute buf1 kh1 ; vmcnt(3)
// FIFO audit (3 loads/phase, drains even-phase ends, steady window 3..9):
// every staged half retires >=1 drain before its consuming phase; regions
// overwritten >=1 closing-barrier after last read. Tail stages wrapped (&31).
// ---------------------------------------------------------------------------
#define QSTAGE_A(SBUF, SKH, STILE)                                            \
    _Pragma("unroll")                                                         \
    for (int j = 0; j < 2; ++j)                                               \
        gl2lds16(gA + soffA[j] + (STILE) * 64 + (SKH) * 32,                   \
                 lds + ((SBUF) * 2 + (SKH)) * 8192 + (j * 512 + w * 64) * 8);

#define QSTAGE_B(SBUF, SKH, STILE)                                            \
    gl2lds16(gB + soffB + (STILE) * 64 + (SKH) * 32,                          \
             lds + 32768 + ((SBUF) * 2 + (SKH)) * 4096 + (w * 64) * 8);

#define QPHASE4(BUF, KH, SBUF, SKH, STILE, DRAIN)                             \
    QSTAGE_A(SBUF, SKH, STILE)                                                \
    QSTAGE_B(SBUF, SKH, STILE)                                                \
    _Pragma("unroll")                                                         \
    for (int mf = 0; mf < 4; ++mf) {                                          \
        int rr = wm + mf * 16 + lm;                                           \
        int slot = rr * 4 + (lq ^ ((rr >> 1) & 3));                           \
        af[mf] = *(const bf16x8*)&lds[((BUF) * 2 + (KH)) * 8192 + slot * 8];  \
    }                                                                         \
    _Pragma("unroll")                                                         \
    for (int nf = 0; nf < 4; ++nf) {                                          \
        int rr = wn + nf * 16 + lm;                                           \
        int slot = rr * 4 + (lq ^ ((rr >> 1) & 3));                           \
        bfr[nf] = *(const bf16x8*)&lds[32768 + ((BUF) * 2 + (KH)) * 4096 + slot * 8]; \
    }                                                                         \
    asm volatile("" ::: "memory");                                            \
    __builtin_amdgcn_s_barrier();                                             \
    __builtin_amdgcn_sched_barrier(0);                                        \
    __builtin_amdgcn_s_setprio(1);                                            \
    _Pragma("unroll")                                                         \
    for (int mf = 0; mf < 4; ++mf)                                            \
        _Pragma("unroll")                                                     \
        for (int nf = 0; nf < 4; ++nf)                                        \
            acc[mf][nf] = __builtin_amdgcn_mfma_f32_16x16x32_bf16(            \
                af[mf], bfr[nf], acc[mf][nf], 0, 0, 0);                       \
    __builtin_amdgcn_s_setprio(0);                                            \
    __builtin_amdgcn_sched_barrier(0);                                        \
    if (DRAIN) { asm volatile("s_waitcnt vmcnt(3)" ::: "memory"); }           \
    asm volatile("" ::: "memory");                                            \
    __builtin_amdgcn_s_barrier();

__global__ __launch_bounds__(512) void gemm_qkv(
    const ushort_t* __restrict__ A, const ushort_t* __restrict__ BT,
    const float* __restrict__ bias,
    ushort_t* __restrict__ qbuf, ushort_t* __restrict__ kbuf,
    ushort_t* __restrict__ vTbuf) {
    __shared__ ushort_t lds[49152];  // 96 KiB
    const int t = threadIdx.x;
    const int w = t >> 6, lane = t & 63, lm = lane & 15, lq = lane >> 4;
    const int wm = (w >> 1) * 64, wn = (w & 1) * 64;
    const int mb = blockIdx.x * 256, nb = blockIdx.y * 128;

    const ushort_t* gA = A + (size_t)mb * HID;
    const ushort_t* gB = BT + (size_t)nb * HID;

    // staging source offsets (inverse of LDS slot swizzle)
    int soffA[2];
#pragma unroll
    for (int j = 0; j < 2; ++j) {
        int r = j * 128 + (t >> 2);
        int c = (t & 3) ^ ((r >> 1) & 3);
        soffA[j] = r * HID + c * 8;
    }
    int soffB;
    {
        int r = t >> 2;
        int c = (t & 3) ^ ((r >> 1) & 3);
        soffB = r * HID + c * 8;
    }

    f32x4 acc[4][4] = {};
    bf16x8 af[4], bfr[4];

    // prologue: buf0 both halves <- T0, buf1 kh0 <- T1 (9 loads), drain
    QSTAGE_A(0, 0, 0) QSTAGE_B(0, 0, 0)
    QSTAGE_A(0, 1, 0) QSTAGE_B(0, 1, 0)
    QSTAGE_A(1, 0, 1) QSTAGE_B(1, 0, 1)
    asm volatile("s_waitcnt vmcnt(0)" ::: "memory");
    __builtin_amdgcn_s_barrier();

#pragma unroll 1
    for (int i = 0; i < 16; ++i) {
        const int Tb = 2 * i + 1;
        const int T2 = (2 * i + 2) & 31, T3 = (2 * i + 3) & 31;
        QPHASE4(0, 0, 1, 1, Tb, 0)
        QPHASE4(0, 1, 0, 0, T2, 1)
        QPHASE4(1, 0, 0, 1, T2, 0)
        QPHASE4(1, 1, 1, 0, T3, 1)
    }

    asm volatile("s_waitcnt vmcnt(0)" ::: "memory");  // drain tail stages

    const int sec = nb >> 11;
    if (sec < 2) {
        // q/k: direct scatter (coalesced in d across lm)
#pragma unroll
        for (int mf = 0; mf < 4; ++mf)
#pragma unroll
            for (int nf = 0; nf < 4; ++nf)
#pragma unroll
                for (int r = 0; r < 4; ++r) {
                    int m = mb + wm + mf * 16 + lq * 4 + r;
                    int c = nb + wn + nf * 16 + lm;
                    float val = acc[mf][nf][r] + bias[c];
                    int hh = (c >> 7) & 15;
                    int d = c & 127;
                    int b = m >> 11, s = m & 2047;
                    size_t bh = (size_t)(b * NH + hh);
                    ushort_t* dst = (sec == 0) ? qbuf : kbuf;
                    dst[(bh * SEQ + s) * HD + d] = f2bf(val);
                }
    } else {
        // v: transpose in LDS (128 d x 256 s), write vT coalesced
        __syncthreads();  // all waves' DMAs drained + reads done
        unsigned* T = (unsigned*)lds;  // [d(128)][132 uints]
        const int b = mb >> 11, sbase = mb & 2047;
        const int hv = (nb >> 7) - 32;
#pragma unroll
        for (int nf = 0; nf < 4; ++nf) {
            const int clc = wn + nf * 16 + lm;  // d 0..127
            const float bb = bias[nb + clc];
#pragma unroll
            for (int mf = 0; mf < 4; ++mf) {
                const int ml = wm + mf * 16 + lq * 4;  // s-local 0..255
#pragma unroll
                for (int r = 0; r < 4; r += 2) {
                    unsigned pk = (unsigned)f2bf(acc[mf][nf][r] + bb) |
                                  ((unsigned)f2bf(acc[mf][nf][r + 1] + bb) << 16);
                    T[clc * 132 + ((ml + r) >> 1)] = pk;
                }
            }
        }
        __syncthreads();
        const int dd = t & 127, sh = t >> 7;  // sh 0..3, 64 s-values each
        ushort_t* vrow = vTbuf +
            ((size_t)(b * NH + hv) * HD + dd) * SEQ + sbase + sh * 64;
#pragma unroll
        for (int ii = 0; ii < 8; ++ii)
            *(uint4*)(vrow + ii * 8) = *(const uint4*)&T[dd * 132 + sh * 32 + ii * 4];
    }
}

// GEMM 2 (m97 structure): out = attn(bf16) @ w_proj + b_proj -> fp32
__global__ __launch_bounds__(256) void gemm_proj(
    const ushort_t* __restrict__ A, const ushort_t* __restrict__ BT,
    const float* __restrict__ bias, float* __restrict__ out) {
    __shared__ ushort_t Abuf[128 * 64];
    __shared__ ushort_t Bbuf[128 * 64];
    ushort_t* At = Abuf;
    ushort_t* Bt = Bbuf;
    const int mb = blockIdx.x * 128;
    const int nb = blockIdx.y * 128;
    GEMM_KLOOP(A, BT)
#pragma unroll
    for (int mt = 0; mt < 4; ++mt)
#pragma unroll
        for (int nt = 0; nt < 4; ++nt)
#pragma unroll
            for (int r = 0; r < 4; ++r) {
                int m = mb + wm + mt * 16 + lq * 4 + r;
                int c = nb + wn + nt * 16 + lm;
                out[(size_t)m * HID + c] = acc[mt][nt][r] + bias[c];
            }
}

// ---------------------------------------------------------------------------
// Flash attention, QBLK=128 (8 waves, 512 thr), single-buffered K/V staging.
// R0==R2 showed dbuf ~= single-buffer (TLP hides staging); so spend LDS on
// work-per-staged-byte: 128 q-rows share each staged K/V tile (staging per
// computed tile halves: 272 vs 528 tile-stagings per (b,h)). LDS 50KB ->
// 2 blocks/CU = 16 waves/CU (2x TLP). Grid 512 = fully co-resident round.
// Causal gating: wave w's diagonal tile ktd = (qbase+w*16)>>6; waves skip
// compute (not barriers) for kt > ktd — wave-uniform branch.
// XCD-pinned mapping: bid = g*8 + (bh&7), g = (15-qt)*4 + (bh>>3).
// + setprio (T5), defer-max (T13, THR=8).
// ---------------------------------------------------------------------------
__global__ __launch_bounds__(512) void attn_kernel(
    const ushort_t* __restrict__ qb, const ushort_t* __restrict__ kbuf,
    const ushort_t* __restrict__ vT, ushort_t* __restrict__ ob) {
    __shared__ ushort_t Ks[64 * 128];   // [key][d] swizzled 16B chunks
    __shared__ ushort_t Vs[128 * 64];   // [d][key] swizzled 16B chunks
    __shared__ ushort_t Ps[8][16 * 72]; // per-wave P, row stride 72

    const int bid = blockIdx.x;
    const int x = bid & 7, g = bid >> 3;
    const int qt = 15 - (g >> 2);
    const int bh = ((g & 3) << 3) | x;
    const int qbase = qt * 128;
    const int t = threadIdx.x, w = t >> 6, lane = t & 63;
    const int lm = lane & 15, lq = lane >> 4;

    const ushort_t* Qg = qb + (size_t)bh * SEQ * HD;
    const ushort_t* Kg = kbuf + (size_t)bh * SEQ * HD;
    const ushort_t* Vg = vT + (size_t)bh * HD * SEQ;

    const float LOG2E = 1.44269504f;
    const int h = bh & 15;
    const float slope2 = exp2f(-0.5f * (float)(h + 1)) * LOG2E;
    const float scale2 = (1.0f / 128.0f) * LOG2E;

    const int qg = qbase + w * 16 + lm;          // this lane's q row
    const int ktd = (qbase + w * 16) >> 6;       // wave's diagonal k-tile

    // Q fragments direct from global (B-operand layout)
    bf16x8 qf[4];
#pragma unroll
    for (int kc = 0; kc < 4; ++kc) {
        uint4 qv = *(const uint4*)(Qg + (size_t)qg * HD + kc * 32 + lq * 8);
        qf[kc] = __builtin_bit_cast(bf16x8, qv);
    }

    float foff[4][4];
#pragma unroll
    for (int mt = 0; mt < 4; ++mt)
#pragma unroll
        for (int r = 0; r < 4; ++r)
            foff[mt][r] = slope2 * (float)(mt * 16 + lq * 4 + r);

    // per-thread swizzled DMA source offsets (512 thr -> 2 loads each)
    int koffs[2], voffs[2];
#pragma unroll
    for (int i = 0; i < 2; ++i) {
        int ci = i * 512 + t;
        int kr = ci >> 4, ks = ci & 15;
        int kcg = (ks & 8) | ((ks & 7) ^ (kr & 7));
        koffs[i] = kr * HD + kcg * 8;
        int vr = ci >> 3, vs = ci & 7;
        int vcg = vs ^ (vr & 7);
        voffs[i] = vr * SEQ + vcg * 8;
    }

    float mrow = -1e30f, lrow = 0.0f;
    f32x4 O[8] = {};
    const int nkt = 2 * qt + 2;

    for (int kt = 0; kt < nkt; ++kt) {
        __syncthreads();  // prev compute's LDS reads done
        {
            const ushort_t* Kt_ = Kg + (size_t)kt * 64 * HD;
            const ushort_t* Vt_ = Vg + (size_t)kt * 64;
#pragma unroll
            for (int i = 0; i < 2; ++i) {
                gl2lds16(Kt_ + koffs[i], Ks + (i * 512 + w * 64) * 8);
                gl2lds16(Vt_ + voffs[i], Vs + (i * 512 + w * 64) * 8);
            }
        }
        __syncthreads();  // staging visible (implicit vmcnt(0) drain)

        if (kt > ktd) continue;  // wave fully masked; barriers stay uniform

        // S^T = K Q^T : per wave 64 keys x 16 q
        f32x4 sacc[4] = {};
        __builtin_amdgcn_s_setprio(1);
#pragma unroll
        for (int kc = 0; kc < 4; ++kc) {
            const int slot = ((kc * 4 + lq) & 8) | (((kc * 4 + lq) & 7) ^ (lm & 7));
#pragma unroll
            for (int mt = 0; mt < 4; ++mt) {
                bf16x8 bk = *(const bf16x8*)&Ks[((mt * 16 + lm) * 16 + slot) * 8];
                sacc[mt] = __builtin_amdgcn_mfma_f32_16x16x32_bf16(bk, qf[kc], sacc[mt], 0, 0, 0);
            }
        }
        __builtin_amdgcn_s_setprio(0);

        // scores (log2 domain); mask only on the wave's diagonal tile
        const float sbase = slope2 * (float)(kt * 64 - qg);
        float sc[4][4];
        if (kt == ktd) {
#pragma unroll
            for (int mt = 0; mt < 4; ++mt)
#pragma unroll
                for (int r = 0; r < 4; ++r) {
                    float s = sacc[mt][r] * scale2 + (sbase + foff[mt][r]);
                    sc[mt][r] = (kt * 64 + mt * 16 + lq * 4 + r <= qg) ? s : -3e38f;
                }
        } else {
#pragma unroll
            for (int mt = 0; mt < 4; ++mt)
#pragma unroll
                for (int r = 0; r < 4; ++r)
                    sc[mt][r] = sacc[mt][r] * scale2 + (sbase + foff[mt][r]);
        }

        // row max
        float tm = sc[0][0];
#pragma unroll
        for (int mt = 0; mt < 4; ++mt)
#pragma unroll
            for (int r = 0; r < 4; ++r) tm = fmaxf(tm, sc[mt][r]);
        tm = fmaxf(tm, __shfl_xor(tm, 16));
        tm = fmaxf(tm, __shfl_xor(tm, 32));

        // defer-max (T13)
        const bool noresc = __all(tm <= mrow + 8.0f) && (kt > 0);
        float mnew, alpha;
        if (noresc) {
            mnew = mrow;
            alpha = 1.0f;
        } else {
            mnew = fmaxf(mrow, tm);
            alpha = __builtin_amdgcn_exp2f(mrow - mnew);
        }
        mrow = mnew;

        // p = exp2(sc - m) -> Ps[q][key], sum
        float psum = 0.0f;
#pragma unroll
        for (int mt = 0; mt < 4; ++mt) {
            float p0 = __builtin_amdgcn_exp2f(sc[mt][0] - mnew);
            float p1 = __builtin_amdgcn_exp2f(sc[mt][1] - mnew);
            float p2 = __builtin_amdgcn_exp2f(sc[mt][2] - mnew);
            float p3 = __builtin_amdgcn_exp2f(sc[mt][3] - mnew);
            psum += (p0 + p1) + (p2 + p3);
            uint2 wv;
            wv.x = ((unsigned)f2bf(p1) << 16) | f2bf(p0);
            wv.y = ((unsigned)f2bf(p3) << 16) | f2bf(p2);
            *(uint2*)&Ps[w][lm * 72 + mt * 16 + lq * 4] = wv;
        }
        psum += __shfl_xor(psum, 16);
        psum += __shfl_xor(psum, 32);
        lrow = lrow * alpha + psum;

        if (!noresc) {
            float av[4];
#pragma unroll
            for (int r = 0; r < 4; ++r) av[r] = __shfl(alpha, lq * 4 + r);
#pragma unroll
            for (int nt = 0; nt < 8; ++nt)
#pragma unroll
                for (int r = 0; r < 4; ++r) O[nt][r] *= av[r];
        }

        // PV: A = P (q=lane&15), B = V^T (swizzled)
        asm volatile("s_waitcnt lgkmcnt(0)" ::: "memory");
        __builtin_amdgcn_s_setprio(1);
#pragma unroll
        for (int kc2 = 0; kc2 < 2; ++kc2) {
            bf16x8 ap = *(const bf16x8*)&Ps[w][lm * 72 + kc2 * 32 + lq * 8];
            const int slot = (kc2 * 4 + lq) ^ (lm & 7);
#pragma unroll
            for (int nt = 0; nt < 8; ++nt) {
                bf16x8 bv = *(const bf16x8*)&Vs[((nt * 16 + lm) * 8 + slot) * 8];
                O[nt] = __builtin_amdgcn_mfma_f32_16x16x32_bf16(ap, bv, O[nt], 0, 0, 0);
            }
        }
        __builtin_amdgcn_s_setprio(0);
    }

    // epilogue
    float lb[4];
#pragma unroll
    for (int r = 0; r < 4; ++r)
        lb[r] = __builtin_amdgcn_rcpf(__shfl(lrow, lq * 4 + r));
    const int b = bh >> 4;
#pragma unroll
    for (int nt = 0; nt < 8; ++nt)
#pragma unroll
        for (int r = 0; r < 4; ++r) {
            int s = qbase + w * 16 + lq * 4 + r;
            int d = nt * 16 + lm;
            ob[((size_t)(b * SEQ + s)) * HID + h * HD + d] = f2bf(O[nt][r] * lb[r]);
        }
}

// ---------------------------------------------------------------------------
extern "C" void kernel_launch(void* const* d_in, const int* in_sizes, int n_in,
                              void* d_out, int out_size, void* d_ws, size_t ws_size,
                              hipStream_t stream) {
    const float* hidden = (const float*)d_in[0];
    const float* w_qkv = (const float*)d_in[1];
    const float* b_qkv = (const float*)d_in[2];
    const float* w_proj = (const float*)d_in[3];
    const float* b_proj = (const float*)d_in[4];
    float* out = (float*)d_out;

    char* ws = (char*)d_ws;
    size_t off = 0;
    ushort_t* wqkvT = (ushort_t*)(ws + off); off += (size_t)NQKV * HID * 2;
    ushort_t* wprojT = (ushort_t*)(ws + off); off += (size_t)HID * HID * 2;
    ushort_t* hbf = (ushort_t*)(ws + off); off += (size_t)BATCH * SEQ * HID * 2;
    ushort_t* qw = (ushort_t*)(ws + off); off += (size_t)BATCH * NH * SEQ * HD * 2;
    ushort_t* kw = (ushort_t*)(ws + off); off += (size_t)BATCH * NH * SEQ * HD * 2;
    ushort_t* vTw = (ushort_t*)(ws + off); off += (size_t)BATCH * NH * SEQ * HD * 2;
    ushort_t* attnw = (ushort_t*)(ws + off); off += (size_t)BATCH * SEQ * HID * 2;

    prep_fused<<<dim3(20480), 256, 0, stream>>>(
        hidden, hbf, w_qkv, wqkvT, w_proj, wprojT);

    gemm_qkv<<<dim3(BATCH * SEQ / 256, NQKV / 128), 512, 0, stream>>>(
        hbf, wqkvT, b_qkv, qw, kw, vTw);

    attn_kernel<<<dim3(BATCH * NH * 16), 512, 0, stream>>>(qw, kw, vTw, attnw);

    gemm_proj<<<dim3(BATCH * SEQ / 128, HID / 128), 256, 0, stream>>>(
        attnw, wprojT, b_proj, out);
}

// Round 7
// 364.276 us; speedup vs baseline: 1.0357x; 1.0020x over previous
//
#include <hip/hip_runtime.h>
#include <hip/hip_bf16.h>

typedef short bf16x8 __attribute__((ext_vector_type(8)));
typedef float f32x4 __attribute__((ext_vector_type(4)));
typedef float f32x16 __attribute__((ext_vector_type(16)));
typedef unsigned short ushort_t;

#define NH 16
#define HD 128
#define SEQ 2048
#define HID 2048
#define NQKV 6144
#define BATCH 2

__device__ __forceinline__ ushort_t f2bf(float x) {
    unsigned u = __builtin_bit_cast(unsigned, x);
    u = (u + 0x7fffu + ((u >> 16) & 1u)) >> 16;
    return (ushort_t)u;
}

// packed f32->bf16 pair (RTNE), low16 = lo, high16 = hi
__device__ __forceinline__ unsigned cvtpk(float lo, float hi) {
    unsigned r;
    asm("v_cvt_pk_bf16_f32 %0, %1, %2" : "=v"(r) : "v"(lo), "v"(hi));
    return r;
}

// async global->LDS, 16B per lane. LDS dest = wave-uniform base + lane*16.
__device__ __forceinline__ void gl2lds16(const ushort_t* g, ushort_t* l) {
    __builtin_amdgcn_global_load_lds(
        (__attribute__((address_space(1))) void*)(g),
        (__attribute__((address_space(3))) void*)(l), 16, 0, 0);
}

// ---------------------------------------------------------------------------
// Fused prep (one launch):
//   blocks [0, 12288):      transpose+cast w_qkv  [HID][NQKV] -> [NQKV][HID]
//   blocks [12288, 16384):  fp32->bf16 hidden states (8 elems/thread)
//   blocks [16384, 20480):  transpose+cast w_proj [HID][HID] -> [HID][HID]
// ---------------------------------------------------------------------------
__global__ __launch_bounds__(256) void prep_fused(
    const float* __restrict__ hidden, ushort_t* __restrict__ hbf,
    const float* __restrict__ wqkv, ushort_t* __restrict__ wqkvT,
    const float* __restrict__ wproj, ushort_t* __restrict__ wprojT) {
    const int bid = blockIdx.x;
    const int t = threadIdx.x;
    if (bid >= 12288 && bid < 16384) {
        int i = (bid - 12288) * 256 + t;
        float4 a0 = *(const float4*)(hidden + (size_t)i * 8);
        float4 a1 = *(const float4*)(hidden + (size_t)i * 8 + 4);
        union { ushort_t u[8]; uint4 v; } p;
        p.u[0]=f2bf(a0.x); p.u[1]=f2bf(a0.y); p.u[2]=f2bf(a0.z); p.u[3]=f2bf(a0.w);
        p.u[4]=f2bf(a1.x); p.u[5]=f2bf(a1.y); p.u[6]=f2bf(a1.z); p.u[7]=f2bf(a1.w);
        *(uint4*)(hbf + (size_t)i * 8) = p.v;
        return;
    }
    const float* w;
    ushort_t* wT;
    int N, bx, by;
    if (bid < 12288) {
        w = wqkv; wT = wqkvT; N = NQKV;
        bx = bid % 192; by = bid / 192;
    } else {
        int b2 = bid - 16384;
        w = wproj; wT = wprojT; N = HID;
        bx = b2 % 64; by = b2 / 64;
    }
    __shared__ float tile[32][33];
    const int nb = bx * 32, kb = by * 32;
    const int tx = t & 31, ty = t >> 5;
#pragma unroll
    for (int i = 0; i < 4; ++i) {
        int k = kb + ty + i * 8;
        tile[ty + i * 8][tx] = w[(size_t)k * N + nb + tx];
    }
    __syncthreads();
#pragma unroll
    for (int i = 0; i < 4; ++i) {
        int n = nb + ty + i * 8;
        wT[(size_t)n * HID + kb + tx] = f2bf(tile[tx][ty + i * 8]);
    }
}

// ---------------------------------------------------------------------------
// m97-style GEMM core: 128x128 tile, BK=64, global_load_lds(16B) staging with
// XOR-swizzled chunk order. LDS[r][slot s] holds global k-chunk s^(r&7).
// (R4/R6 established this is the practical ceiling for this grid shape.)
// ---------------------------------------------------------------------------
#define GEMM_KLOOP(A_, BT_)                                                     \
    const int t = threadIdx.x;                                                  \
    const int w = t >> 6, lane = t & 63, lm = lane & 15, lq = lane >> 4;        \
    const int wm = (w >> 1) * 64, wn = (w & 1) * 64;                            \
    const int lrow = lane >> 3, lsw = (lane & 7) ^ lrow;                        \
    f32x4 acc[4][4] = {};                                                       \
    const ushort_t* gA = A_ + (size_t)(mb + w * 32 + lrow) * HID + lsw * 8;     \
    const ushort_t* gB = BT_ + (size_t)(nb + w * 32 + lrow) * HID + lsw * 8;    \
    for (int kb = 0; kb < HID; kb += 64) {                                      \
        __syncthreads();                                                        \
        _Pragma("unroll")                                                       \
        for (int c = 0; c < 4; ++c) {                                           \
            gl2lds16(gA + (size_t)c * 8 * HID + kb, At + (w * 256 + c * 64) * 8); \
            gl2lds16(gB + (size_t)c * 8 * HID + kb, Bt + (w * 256 + c * 64) * 8); \
        }                                                                       \
        __syncthreads();                                                        \
        _Pragma("unroll")                                                       \
        for (int kc = 0; kc < 2; ++kc) {                                        \
            const int slot = (kc * 4 + lq) ^ (lm & 7);                          \
            bf16x8 af[4], bfr[4];                                               \
            _Pragma("unroll")                                                   \
            for (int mt = 0; mt < 4; ++mt)                                      \
                af[mt] = ((const bf16x8*)At)[(wm + mt * 16 + lm) * 8 + slot];   \
            _Pragma("unroll")                                                   \
            for (int nt = 0; nt < 4; ++nt)                                      \
                bfr[nt] = ((const bf16x8*)Bt)[(wn + nt * 16 + lm) * 8 + slot];  \
            _Pragma("unroll")                                                   \
            for (int mt = 0; mt < 4; ++mt)                                      \
                _Pragma("unroll")                                               \
                for (int nt = 0; nt < 4; ++nt)                                  \
                    acc[mt][nt] = __builtin_amdgcn_mfma_f32_16x16x32_bf16(      \
                        af[mt], bfr[nt], acc[mt][nt], 0, 0, 0);                 \
        }                                                                       \
    }

// ---------------------------------------------------------------------------
// GEMM 1: qkv = hidden(bf16) @ w_qkv + b_qkv   (m97 structure, 121 us)
// q,k -> [B,nh,S,hd]; v -> vT [B,nh,hd,S] via in-LDS transpose.
// ---------------------------------------------------------------------------
__global__ __launch_bounds__(256) void gemm_qkv(
    const ushort_t* __restrict__ A, const ushort_t* __restrict__ BT,
    const float* __restrict__ bias,
    ushort_t* __restrict__ qbuf, ushort_t* __restrict__ kbuf,
    ushort_t* __restrict__ vTbuf) {
    __shared__ unsigned shbuf[128 * 68];  // 34KB: staging (32KB) / transpose T
    ushort_t* At = (ushort_t*)shbuf;
    ushort_t* Bt = At + 128 * 64;
    const int mb = blockIdx.x * 128;
    const int nb = blockIdx.y * 128;
    GEMM_KLOOP(A, BT)

    const int sec = nb >> 11;
    if (sec < 2) {
        // q/k: direct scatter (coalesced in d across lm)
#pragma unroll
        for (int mt = 0; mt < 4; ++mt)
#pragma unroll
            for (int nt = 0; nt < 4; ++nt)
#pragma unroll
                for (int r = 0; r < 4; ++r) {
                    int m = mb + wm + mt * 16 + lq * 4 + r;
                    int c = nb + wn + nt * 16 + lm;
                    float val = acc[mt][nt][r] + bias[c];
                    int h = (c >> 7) & 15;
                    int d = c & 127;
                    int b = m >> 11, s = m & 2047;
                    size_t bh = (size_t)(b * NH + h);
                    ushort_t* dst = (sec == 0) ? qbuf : kbuf;
                    dst[(bh * SEQ + s) * HD + d] = f2bf(val);
                }
    } else {
        // v: transpose in LDS, write vT[bh][d][s] coalesced
        __syncthreads();
        unsigned* T = shbuf;  // [c(128)][68 uints]
#pragma unroll
        for (int mt = 0; mt < 4; ++mt)
#pragma unroll
            for (int nt = 0; nt < 4; ++nt) {
                const int cl = wn + nt * 16 + lm;       // d 0..127
                const int ml = wm + mt * 16 + lq * 4;   // s-local base
                const float bb = bias[nb + cl];
#pragma unroll
                for (int r = 0; r < 4; r += 2) {
                    unsigned pk = (unsigned)f2bf(acc[mt][nt][r] + bb) |
                                  ((unsigned)f2bf(acc[mt][nt][r + 1] + bb) << 16);
                    T[cl * 68 + ((ml + r) >> 1)] = pk;
                }
            }
        __syncthreads();
        const int d = t & 127, sh = t >> 7;
        const int b = mb >> 11, sbase = mb & 2047;
        const int hv = (nb >> 7) - 32;
        ushort_t* vrow = vTbuf + ((size_t)(b * NH + hv) * HD + d) * SEQ + sbase + sh * 64;
#pragma unroll
        for (int i = 0; i < 8; ++i)
            *(uint4*)(vrow + i * 8) = *(const uint4*)&T[d * 68 + sh * 32 + i * 4];
    }
}

// GEMM 2: out = attn(bf16) @ w_proj + b_proj -> fp32
__global__ __launch_bounds__(256) void gemm_proj(
    const ushort_t* __restrict__ A, const ushort_t* __restrict__ BT,
    const float* __restrict__ bias, float* __restrict__ out) {
    __shared__ ushort_t Abuf[128 * 64];
    __shared__ ushort_t Bbuf[128 * 64];
    ushort_t* At = Abuf;
    ushort_t* Bt = Bbuf;
    const int mb = blockIdx.x * 128;
    const int nb = blockIdx.y * 128;
    GEMM_KLOOP(A, BT)
#pragma unroll
    for (int mt = 0; mt < 4; ++mt)
#pragma unroll
        for (int nt = 0; nt < 4; ++nt)
#pragma unroll
            for (int r = 0; r < 4; ++r) {
                int m = mb + wm + mt * 16 + lq * 4 + r;
                int c = nb + wn + nt * 16 + lm;
                out[(size_t)m * HID + c] = acc[mt][nt][r] + bias[c];
            }
}

// ---------------------------------------------------------------------------
// Flash attention — 32x32 swapped-operand rebuild (m214-style, T12):
//   QK^T: mfma_32x32x16(A=K, B=Q) -> S[key_regs][q=lane&31]; the whole
//   softmax state (max/sum/alpha/1/l) is PER-LANE SCALAR (q = lane&31 for
//   both halves): row-reduce = 31 in-lane fmax + 1 shfl_xor(32); O-rescale
//   needs no shuffles.
//   PV: mfma_32x32x16(A=V^T, B=P^T) -> O[d_regs][q=lane&31]. P stays in
//   registers: cvt_pk_bf16 pairs + shfl_xor(32) half-exchange assemble the
//   B-fragments (no P LDS round-trip, no lgkmcnt(0) serialization).
// Key bookkeeping (C-layout row r(reg,hl) = (reg&3)+8*(reg>>2)+4*hl, hl =
// lane>>5): p-reg group G=0..7 holds keys 8*(G&3)+32*(G>>2)+4*hl+{0..3}.
// PV k-step ks needs keys 16ks+8*hl+{0..7} = own group (2ks+hl) half + the
// partner half's group exchanged via shfl_xor(,32).
// 4 waves x 32 q = QBLK 128; KVBLK 64; single-buffered K/V via gl2lds with
// the R2-verified XOR chunk swizzle. Grid 512, XCD-pinned, LPT order.
// ---------------------------------------------------------------------------
__global__ __launch_bounds__(256) void attn_kernel(
    const ushort_t* __restrict__ qb, const ushort_t* __restrict__ kbuf,
    const ushort_t* __restrict__ vT, ushort_t* __restrict__ ob) {
    __shared__ ushort_t Ks[64 * 128];   // [key][d] swizzled 16B chunks
    __shared__ ushort_t Vs[128 * 64];   // [d][key] swizzled 16B chunks

    const int bid = blockIdx.x;
    const int x = bid & 7, g = bid >> 3;
    const int qt = 15 - (g >> 2);
    const int bh = ((g & 3) << 3) | x;
    const int qbase = qt * 128;
    const int t = threadIdx.x, w = t >> 6, lane = t & 63;
    const int l31 = lane & 31, hl = lane >> 5;

    const ushort_t* Qg = qb + (size_t)bh * SEQ * HD;
    const ushort_t* Kg = kbuf + (size_t)bh * SEQ * HD;
    const ushort_t* Vg = vT + (size_t)bh * HD * SEQ;

    const int h = bh & 15;
    const float LOG2E = 1.44269504f;
    const float slope2 = exp2f(-0.5f * (float)(h + 1)) * LOG2E;
    const float scale2 = (1.0f / 128.0f) * LOG2E;

    const int qrow = qbase + w * 32 + l31;           // this lane's q (both halves)
    const int ktd = (qbase + w * 32 + 31) >> 6;      // wave's diagonal k-tile

    // Q B-fragments: lane supplies Q[qrow][d = (2s+hl)*8 .. +8] for step s
    bf16x8 qf[8];
#pragma unroll
    for (int s = 0; s < 8; ++s) {
        uint4 qv = *(const uint4*)(Qg + (size_t)qrow * HD + (2 * s + hl) * 8);
        qf[s] = __builtin_bit_cast(bf16x8, qv);
    }

    // staging source offsets (R2-verified): LDS linear ci=i*256+t holds
    // K chunk (ks&8)|((ks&7)^(kr&7)) of key-row kr; V chunk vs^(vr&7) of d-row vr
    int koffs[4], voffs[4];
#pragma unroll
    for (int i = 0; i < 4; ++i) {
        int ci = i * 256 + t;
        int kr = ci >> 4, ks = ci & 15;
        int kcg = (ks & 8) | ((ks & 7) ^ (kr & 7));
        koffs[i] = kr * HD + kcg * 8;
        int vr = ci >> 3, vs = ci & 7;
        int vcg = vs ^ (vr & 7);
        voffs[i] = vr * SEQ + vcg * 8;
    }

    float mrow = -1e30f, lrow = 0.0f;
    f32x16 O[4] = {};
    const int nkt = 2 * qt + 2;

    for (int kt = 0; kt < nkt; ++kt) {
        __syncthreads();  // prev compute's LDS reads done
        {
            const ushort_t* Kt_ = Kg + (size_t)kt * 64 * HD;
            const ushort_t* Vt_ = Vg + (size_t)kt * 64;
#pragma unroll
            for (int i = 0; i < 4; ++i) {
                gl2lds16(Kt_ + koffs[i], Ks + (i * 256 + w * 64) * 8);
                gl2lds16(Vt_ + voffs[i], Vs + (i * 256 + w * 64) * 8);
            }
        }
        __syncthreads();  // staging visible (implicit vmcnt(0) drain)

        if (kt > ktd) continue;  // wave fully masked; barriers stay uniform

        // ---- QK^T: S[key][q], 2 key-subtiles x 8 d-steps ----
        f32x16 s0 = {}, s1 = {};
        __builtin_amdgcn_s_setprio(1);
#pragma unroll
        for (int s = 0; s < 8; ++s) {
            const int c = 2 * s + hl;                      // d-chunk
            const int slot = (c & 8) | ((c & 7) ^ (l31 & 7));
            bf16x8 k0 = *(const bf16x8*)&Ks[(l31 * 16 + slot) * 8];
            bf16x8 k1 = *(const bf16x8*)&Ks[((32 + l31) * 16 + slot) * 8];
            s0 = __builtin_amdgcn_mfma_f32_32x32x16_bf16(k0, qf[s], s0, 0, 0, 0);
            s1 = __builtin_amdgcn_mfma_f32_32x32x16_bf16(k1, qf[s], s1, 0, 0, 0);
        }
        __builtin_amdgcn_s_setprio(0);

        // ---- scores (log2 domain) + mask on diagonal tile ----
        const float sb = slope2 * (float)(kt * 64 + 4 * hl - qrow);
        float tm = -3e38f;
        if (kt == ktd) {
#pragma unroll
            for (int r = 0; r < 16; ++r) {
                const int Cr = (r & 3) + 8 * (r >> 2);
                float v0 = s0[r] * scale2 + (sb + slope2 * (float)Cr);
                float v1 = s1[r] * scale2 + (sb + slope2 * (float)(Cr + 32));
                int k0i = kt * 64 + Cr + 4 * hl;
                v0 = (k0i <= qrow) ? v0 : -3e38f;
                v1 = (k0i + 32 <= qrow) ? v1 : -3e38f;
                s0[r] = v0; s1[r] = v1;
                tm = fmaxf(tm, fmaxf(v0, v1));
            }
        } else {
#pragma unroll
            for (int r = 0; r < 16; ++r) {
                const int Cr = (r & 3) + 8 * (r >> 2);
                float v0 = s0[r] * scale2 + (sb + slope2 * (float)Cr);
                float v1 = s1[r] * scale2 + (sb + slope2 * (float)(Cr + 32));
                s0[r] = v0; s1[r] = v1;
                tm = fmaxf(tm, fmaxf(v0, v1));
            }
        }
        tm = fmaxf(tm, __shfl_xor(tm, 32));  // partner half, same q

        // defer-max (T13, THR=8 in log2 domain)
        const bool noresc = __all(tm <= mrow + 8.0f) && (kt > 0);
        float mnew, alpha;
        if (noresc) { mnew = mrow; alpha = 1.0f; }
        else { mnew = fmaxf(mrow, tm); alpha = __builtin_amdgcn_exp2f(mrow - mnew); }
        mrow = mnew;

        // p = exp2(sc - m), per-lane row sum
        float psum = 0.0f;
#pragma unroll
        for (int r = 0; r < 16; ++r) {
            float p0 = __builtin_amdgcn_exp2f(s0[r] - mnew);
            float p1 = __builtin_amdgcn_exp2f(s1[r] - mnew);
            s0[r] = p0; s1[r] = p1;
            psum += p0 + p1;
        }
        psum += __shfl_xor(psum, 32);
        lrow = lrow * alpha + psum;

        if (!noresc) {
#pragma unroll
            for (int dt = 0; dt < 4; ++dt)
#pragma unroll
                for (int r = 0; r < 16; ++r) O[dt][r] *= alpha;
        }

        // ---- pack P to bf16 pairs: group G holds keys 8*(G&3)+32*(G>>2)+4hl+{0..3}
        unsigned c0[8], c1[8];
#pragma unroll
        for (int G = 0; G < 4; ++G) {
            c0[G]     = cvtpk(s0[4 * G + 0], s0[4 * G + 1]);
            c1[G]     = cvtpk(s0[4 * G + 2], s0[4 * G + 3]);
            c0[4 + G] = cvtpk(s1[4 * G + 0], s1[4 * G + 1]);
            c1[4 + G] = cvtpk(s1[4 * G + 2], s1[4 * G + 3]);
        }

        // ---- PV: O[d][q] += V^T x P^T, 4 k-steps x 4 d-tiles ----
        __builtin_amdgcn_s_setprio(1);
#pragma unroll
        for (int ks = 0; ks < 4; ++ks) {
            // assemble B-frag: keys 16ks + 8*hl + {0..7} for column q
            unsigned a0 = c0[2 * ks], a1 = c1[2 * ks];
            unsigned b0 = c0[2 * ks + 1], b1 = c1[2 * ks + 1];
            unsigned own0 = hl ? b0 : a0, own1 = hl ? b1 : a1;   // my 4 keys
            unsigned snd0 = hl ? a0 : b0, snd1 = hl ? a1 : b1;   // partner's need
            unsigned rcv0 = __shfl_xor(snd0, 32);
            unsigned rcv1 = __shfl_xor(snd1, 32);
            union { unsigned u[4]; bf16x8 v; } pf;
            pf.u[0] = hl ? rcv0 : own0;
            pf.u[1] = hl ? rcv1 : own1;
            pf.u[2] = hl ? own0 : rcv0;
            pf.u[3] = hl ? own1 : rcv1;
            const int c = 2 * ks + hl;                      // key-chunk in Vs
#pragma unroll
            for (int dt = 0; dt < 4; ++dt) {
                const int vr = dt * 32 + l31;
                const int slot = c ^ (vr & 7);
                bf16x8 vf = *(const bf16x8*)&Vs[(vr * 8 + slot) * 8];
                O[dt] = __builtin_amdgcn_mfma_f32_32x32x16_bf16(vf, pf.v, O[dt], 0, 0, 0);
            }
        }
        __builtin_amdgcn_s_setprio(0);
    }

    // epilogue: O[d = dt*32 + 8*g4 + 4*hl + r3][q = qrow] / lrow
    const float lb = __builtin_amdgcn_rcpf(lrow);
    const int b = bh >> 4;
    ushort_t* orow = ob + ((size_t)(b * SEQ + qrow)) * HID + h * HD;
#pragma unroll
    for (int dt = 0; dt < 4; ++dt)
#pragma unroll
        for (int g4 = 0; g4 < 4; ++g4) {
            union { ushort_t u[4]; uint2 v; } pk;
            pk.u[0] = f2bf(O[dt][4 * g4 + 0] * lb);
            pk.u[1] = f2bf(O[dt][4 * g4 + 1] * lb);
            pk.u[2] = f2bf(O[dt][4 * g4 + 2] * lb);
            pk.u[3] = f2bf(O[dt][4 * g4 + 3] * lb);
            *(uint2*)(orow + dt * 32 + 8 * g4 + 4 * hl) = pk.v;
        }
}

// ---------------------------------------------------------------------------
extern "C" void kernel_launch(void* const* d_in, const int* in_sizes, int n_in,
                              void* d_out, int out_size, void* d_ws, size_t ws_size,
                              hipStream_t stream) {
    const float* hidden = (const float*)d_in[0];
    const float* w_qkv = (const float*)d_in[1];
    const float* b_qkv = (const float*)d_in[2];
    const float* w_proj = (const float*)d_in[3];
    const float* b_proj = (const float*)d_in[4];
    float* out = (float*)d_out;

    char* ws = (char*)d_ws;
    size_t off = 0;
    ushort_t* wqkvT = (ushort_t*)(ws + off); off += (size_t)NQKV * HID * 2;
    ushort_t* wprojT = (ushort_t*)(ws + off); off += (size_t)HID * HID * 2;
    ushort_t* hbf = (ushort_t*)(ws + off); off += (size_t)BATCH * SEQ * HID * 2;
    ushort_t* qw = (ushort_t*)(ws + off); off += (size_t)BATCH * NH * SEQ * HD * 2;
    ushort_t* kw = (ushort_t*)(ws + off); off += (size_t)BATCH * NH * SEQ * HD * 2;
    ushort_t* vTw = (ushort_t*)(ws + off); off += (size_t)BATCH * NH * SEQ * HD * 2;
    ushort_t* attnw = (ushort_t*)(ws + off); off += (size_t)BATCH * SEQ * HID * 2;

    prep_fused<<<dim3(20480), 256, 0, stream>>>(
        hidden, hbf, w_qkv, wqkvT, w_proj, wprojT);

    gemm_qkv<<<dim3(BATCH * SEQ / 128, NQKV / 128), 256, 0, stream>>>(
        hbf, wqkvT, b_qkv, qw, kw, vTw);

    attn_kernel<<<dim3(BATCH * NH * 16), 256, 0, stream>>>(qw, kw, vTw, attnw);

    gemm_proj<<<dim3(BATCH * SEQ / 128, HID / 128), 256, 0, stream>>>(
        attnw, wprojT, b_proj, out);
}